// Round 6
// baseline (82.325 us; speedup 1.0000x reference)
//
#include <hip/hip_runtime.h>
#include <math.h>

#define BLOCK 256

__device__ __forceinline__ float fast_rcp(float x) {
    return __builtin_amdgcn_rcpf(x);
}
// HW sin/cos: v_sin_f32/v_cos_f32 take revolutions; |arg| < 1 rev here -> full accuracy
__device__ __forceinline__ float fsin(float x) {
    return __builtin_amdgcn_sinf(x * 0.15915494309189535f);
}
__device__ __forceinline__ float fcos(float x) {
    return __builtin_amdgcn_cosf(x * 0.15915494309189535f);
}

// L1 "diamond" pseudo-angle: strictly monotone in atan2(y,x); (0,0) -> 0.
__device__ __forceinline__ float pseudo_angle(float x, float y) {
    float d = fabsf(x) + fabsf(y);
    float p = (d == 0.f) ? 1.f : x * fast_rcp(d);
    return (y < 0.f) ? (p - 1.f) : (1.f - p);
}

// Running-shoelace state: first point, prev point, accumulator.
struct Shoe {
    float sfx, sfy, spx, spy, acc;
    bool have;
};

__device__ __forceinline__ void emit(Shoe& s, bool c, float X, float Y) {
    float cr = s.spx * Y - s.spy * X;
    s.acc += (c && s.have) ? cr : 0.f;
    s.sfx = (c && !s.have) ? X : s.sfx;
    s.sfy = (c && !s.have) ? Y : s.sfy;
    s.spx = c ? X : s.spx;
    s.spy = c ? Y : s.spy;
    s.have = s.have || c;
}

// SH edge (a->b) clipped against y in [-hh, hh], emissions into running shoelace.
__device__ __forceinline__ void edge_clip_y(Shoe& s, bool en, float ax, float ay,
                                            float bx, float by, float hh) {
    bool inA = en && (ay <= hh) && (ay >= -hh);
    bool cA = en && ((ay > hh) != (by > hh));
    bool cB = en && ((ay < -hh) != (by < -hh));
    float dxe = bx - ax, dye = by - ay;
    float rd = fast_rcp(dye);
    float tA = (hh - ay) * rd;
    float tB = (-hh - ay) * rd;
    float xA = fmaf(tA, dxe, ax);
    float xB = fmaf(tB, dxe, ax);
    bool fA = cA && (!cB || (tA <= tB));
    float e1x = fA ? xA : xB, e1y = fA ? hh : -hh;
    float e2x = fA ? xB : xA, e2y = fA ? -hh : hh;
    emit(s, inA, ax, ay);
    emit(s, cA || cB, e1x, e1y);
    emit(s, cA && cB, e2x, e2y);
}

__launch_bounds__(BLOCK)
__global__ void giou_kernel(const float* __restrict__ pred,
                            const float* __restrict__ target,
                            const float* __restrict__ weight,
                            float* __restrict__ partials, int N) {
    // NO LDS anywhere: occupancy limited only by VGPRs; no lgkmcnt chains.
    int tid = threadIdx.x;
    long gi = (long)blockIdx.x * BLOCK + tid;
    int i = (gi < (long)N) ? (int)gi : (N - 1);

    float p[5], q[5];
#pragma unroll
    for (int j = 0; j < 5; ++j) p[j] = pred[i * 5 + j];
#pragma unroll
    for (int j = 0; j < 5; ++j) q[j] = target[i * 5 + j];
    float wgt = weight[i];

    // ---- everything in box2's local frame (areas are rotation-invariant) ----
    float cq = fcos(q[4]), sq = fsin(q[4]);
    float dang = p[4] - q[4];
    float cd = fcos(dang), sd = fsin(dang);
    float hw = 0.5f * q[2], hh = 0.5f * q[3];   // box2 = [-hw,hw]x[-hh,hh]
    float dxc = p[0] - q[0], dyc = p[1] - q[1];
    float tx = dxc * cq + dyc * sq;
    float ty = -dxc * sq + dyc * cq;
    float ax_ = 0.5f * p[2] * cd, ay_ = 0.5f * p[2] * sd;   // 0.5*w1*(cd,sd)
    float bx_ = -0.5f * p[3] * sd, by_ = 0.5f * p[3] * cd;  // 0.5*h1*(-sd,cd)

    // box1 corners in frame, CCW, same (dx,dy) pattern as reference
    float qx[4], qy[4];
    qx[0] = tx + ax_ + bx_; qy[0] = ty + ay_ + by_;
    qx[1] = tx - ax_ + bx_; qy[1] = ty - ay_ + by_;
    qx[2] = tx - ax_ - bx_; qy[2] = ty - ay_ - by_;
    qx[3] = tx + ax_ - bx_; qy[3] = ty + ay_ - by_;

    // ---- slab 1: clip quad against x in [-hw, hw] -> 8 fixed register slots ----
    float sxk[8], syk[8];
    bool sv[8];
#pragma unroll
    for (int e = 0; e < 4; ++e) {
        int en = (e + 1) & 3;
        float xc = qx[e], yc = qy[e], xn = qx[en], yn = qy[en];
        float dxe = xn - xc, dye = yn - yc;
        bool inC = (xc <= hw) && (xc >= -hw);
        bool cA = (xc > hw) != (xn > hw);
        bool cB = (xc < -hw) != (xn < -hw);
        float rd = fast_rcp(dxe);
        float tA = (hw - xc) * rd;
        float tB = (-hw - xc) * rd;
        float yA = fmaf(tA, dye, yc);
        float yB = fmaf(tB, dye, yc);
        bool fA = cA && (!cB || (tA <= tB));
        float X1x = fA ? hw : -hw, X1y = fA ? yA : yB;
        float X2x = fA ? -hw : hw, X2y = fA ? yB : yA;
        sxk[2 * e]     = inC ? xc : X1x;
        syk[2 * e]     = inC ? yc : X1y;
        sv[2 * e]      = inC || cA || cB;
        sxk[2 * e + 1] = inC ? X1x : X2x;
        syk[2 * e + 1] = inC ? X1y : X2y;
        sv[2 * e + 1]  = inC ? (cA || cB) : (cA && cB);
    }

    // ---- slab 2 (y in [-hh,hh]) fused with running shoelace, all registers ----
    Shoe sh; sh.sfx = sh.sfy = sh.spx = sh.spy = sh.acc = 0.f; sh.have = false;
    bool have_p = false;
    float pfx = 0.f, pfy = 0.f, pvx = 0.f, pvy = 0.f;
#pragma unroll
    for (int k = 0; k < 8; ++k) {
        bool val = sv[k];
        float cx_ = sxk[k], cy_ = syk[k];
        edge_clip_y(sh, have_p && val, pvx, pvy, cx_, cy_, hh);
        pfx = (val && !have_p) ? cx_ : pfx;
        pfy = (val && !have_p) ? cy_ : pfy;
        pvx = val ? cx_ : pvx;
        pvy = val ? cy_ : pvy;
        have_p = have_p || val;
    }
    edge_clip_y(sh, have_p, pvx, pvy, pfx, pfy, hh);   // wrap edge (last -> first)
    float wrap = sh.spx * sh.sfy - sh.spy * sh.sfx;    // close shoelace
    float accs = sh.acc + (sh.have ? wrap : 0.f);
    float overlap = 0.5f * fabsf(accs);

    // ---- enclose: 8 frame points, reference-faithful sorted shoelace ----
    // rank (stable) + REGISTER GATHER (ranks are a permutation of 0..7) —
    // replaces the LDS scatter: zero memory latency, pure cndmask ILP.
    float enc;
    {
        float px8[8], py8[8];
#pragma unroll
        for (int j = 0; j < 4; ++j) { px8[j] = qx[j]; py8[j] = qy[j]; }
        px8[4] = hw;  py8[4] = hh;
        px8[5] = -hw; py8[5] = hh;
        px8[6] = -hw; py8[6] = -hh;
        px8[7] = hw;  py8[7] = -hh;
        float ex = 0.f, ey = 0.f;
#pragma unroll
        for (int j = 0; j < 8; ++j) { ex += px8[j]; ey += py8[j]; }
        float mx = ex * 0.125f, my = ey * 0.125f;
        float ang[8];
#pragma unroll
        for (int j = 0; j < 8; ++j) ang[j] = pseudo_angle(px8[j] - mx, py8[j] - my);
        int rnk[8];
#pragma unroll
        for (int j = 0; j < 8; ++j) {
            int r = 0;
#pragma unroll
            for (int k = 0; k < 8; ++k) {
                if (k < j)      r += (ang[k] <= ang[j]) ? 1 : 0;
                else if (k > j) r += (ang[k] <  ang[j]) ? 1 : 0;
            }
            rnk[j] = r;
        }
        float sx0[8], sy0[8];
#pragma unroll
        for (int k = 0; k < 8; ++k) { sx0[k] = 0.f; sy0[k] = 0.f; }
#pragma unroll
        for (int j = 0; j < 8; ++j) {
#pragma unroll
            for (int k = 0; k < 8; ++k) {
                bool hit = (rnk[j] == k);
                sx0[k] = hit ? px8[j] : sx0[k];
                sy0[k] = hit ? py8[j] : sy0[k];
            }
        }
        float acc2 = 0.f;
#pragma unroll
        for (int k = 0; k < 8; ++k) {
            int kn = (k + 1) & 7;
            acc2 += sx0[k] * sy0[kn] - sy0[k] * sx0[kn];
        }
        enc = 0.5f * fabsf(acc2);
    }

    // ---- GIoU loss ----
    float area1 = p[2] * p[3];
    float area2 = q[2] * q[3];
    float uni = area1 + area2 - overlap + 1e-6f;
    float iou = fmaxf(overlap / uni, 1e-6f);
    float giou = iou - (enc - uni) / enc;
    float loss = (1.f - giou) * wgt;
    if (gi >= (long)N) loss = 0.f;

    // wave-64 reduce -> one plain store per wave (no global atomics)
#pragma unroll
    for (int off = 32; off > 0; off >>= 1)
        loss += __shfl_down(loss, off, 64);
    if ((tid & 63) == 0)
        partials[blockIdx.x * (BLOCK / 64) + (tid >> 6)] = loss;
}

// Deterministic final reduce: one 1024-thread block over the partials.
__launch_bounds__(1024)
__global__ void reduce_kernel(const float* __restrict__ partials,
                              float* __restrict__ out, int nparts, float scale) {
    __shared__ float acc[16];
    int tid = threadIdx.x;
    float s = 0.f;
    for (int j = tid; j < nparts; j += 1024) s += partials[j];
#pragma unroll
    for (int off = 32; off > 0; off >>= 1)
        s += __shfl_down(s, off, 64);
    if ((tid & 63) == 0) acc[tid >> 6] = s;
    __syncthreads();
    if (tid == 0) {
        float t = 0.f;
#pragma unroll
        for (int k = 0; k < 16; ++k) t += acc[k];
        out[0] = t * scale;
    }
}

extern "C" void kernel_launch(void* const* d_in, const int* in_sizes, int n_in,
                              void* d_out, int out_size, void* d_ws, size_t ws_size,
                              hipStream_t stream) {
    const float* pred   = (const float*)d_in[0];
    const float* target = (const float*)d_in[1];
    const float* weight = (const float*)d_in[2];
    float* out = (float*)d_out;
    float* ws  = (float*)d_ws;
    int N = in_sizes[0] / 5;

    int nblocks = (N + BLOCK - 1) / BLOCK;
    int nparts = nblocks * (BLOCK / 64);
    giou_kernel<<<nblocks, BLOCK, 0, stream>>>(pred, target, weight, ws, N);
    reduce_kernel<<<1, 1024, 0, stream>>>(ws, out, nparts, 1.0f / (float)N);
}